// Round 1
// baseline (143.800 us; speedup 1.0000x reference)
//
#include <hip/hip_runtime.h>
#include <math.h>

#define C_ 256
#define R_ 16
#define B_ 8
#define H_ 128
#define W_ 128
#define HW_ (H_ * W_)

__device__ __forceinline__ float sigmoidf_(float z) {
    return 1.0f / (1.0f + __expf(-z));
}

// m[c] = mean over o of dct_w[o, c]
__global__ void k_colmean(const float* __restrict__ dct_w, float* __restrict__ m) {
    int c = threadIdx.x;
    float s = 0.0f;
    for (int o = 0; o < C_; ++o) s += dct_w[o * C_ + c];
    m[c] = s * (1.0f / C_);
}

// Per-(b,c) mean and max over HW. One block per (b,c), contiguous 64 KiB.
__global__ void k_colstats(const float* __restrict__ x,
                           float* __restrict__ yavg, float* __restrict__ ymax) {
    int bc = blockIdx.x;
    const float4* p = (const float4*)(x + (size_t)bc * HW_);
    float s = 0.0f;
    float mx = -3.402823466e+38f;
    for (int i = threadIdx.x; i < HW_ / 4; i += 256) {
        float4 v = p[i];
        s += v.x + v.y + v.z + v.w;
        mx = fmaxf(mx, fmaxf(fmaxf(v.x, v.y), fmaxf(v.z, v.w)));
    }
    // wave64 reduce
    for (int off = 32; off > 0; off >>= 1) {
        s += __shfl_down(s, off);
        mx = fmaxf(mx, __shfl_down(mx, off));
    }
    __shared__ float ss[4], sm[4];
    int wid = threadIdx.x >> 6, lane = threadIdx.x & 63;
    if (lane == 0) { ss[wid] = s; sm[wid] = mx; }
    __syncthreads();
    if (threadIdx.x == 0) {
        float S = ss[0] + ss[1] + ss[2] + ss[3];
        float M = fmaxf(fmaxf(sm[0], sm[1]), fmaxf(sm[2], sm[3]));
        yavg[bc] = S * (1.0f / HW_);
        ymax[bc] = M;
    }
}

// temp[b,hw] = sum_c m[c] * x[b,c,hw].  256 blocks (8 images x 32 chunks),
// each thread owns 2 pixels (float2), loops over 256 channels.
__global__ void k_temp(const float* __restrict__ x, const float* __restrict__ m,
                       float* __restrict__ temp) {
    __shared__ float sm_[C_];
    sm_[threadIdx.x] = m[threadIdx.x];
    __syncthreads();
    int b = blockIdx.x >> 5;
    int chunk = blockIdx.x & 31;
    int pix = chunk * 512 + threadIdx.x * 2;
    const float2* px = (const float2*)(x + (size_t)b * C_ * HW_ + pix);
    float ax = 0.0f, ay = 0.0f;
    for (int c = 0; c < C_; ++c) {
        float2 v = px[(size_t)c * (HW_ / 2)];
        float w = sm_[c];
        ax = fmaf(w, v.x, ax);
        ay = fmaf(w, v.y, ay);
    }
    float2* t = (float2*)(temp + b * HW_ + pix);
    float2 r; r.x = ax; r.y = ay;
    *t = r;
}

// SE MLP: channel_att[b,c] = sigmoid(fc2(relu(fc1(y_avg)))) + same for y_max.
// One block per image.
__global__ void k_fc(const float* __restrict__ ya, const float* __restrict__ ym,
                     const float* __restrict__ w1, const float* __restrict__ b1,
                     const float* __restrict__ w2, const float* __restrict__ b2,
                     float* __restrict__ att) {
    int b = blockIdx.x;
    __shared__ float sa[C_], smx[C_], ha[R_], hm[R_];
    sa[threadIdx.x] = ya[b * C_ + threadIdx.x];
    smx[threadIdx.x] = ym[b * C_ + threadIdx.x];
    __syncthreads();
    if (threadIdx.x < 2 * R_) {
        int j = threadIdx.x & (R_ - 1);
        bool isMax = threadIdx.x >= R_;
        const float* y = isMax ? smx : sa;
        float s = b1[j];
        for (int c = 0; c < C_; ++c) s = fmaf(w1[j * C_ + c], y[c], s);
        s = fmaxf(s, 0.0f);
        (isMax ? hm : ha)[j] = s;
    }
    __syncthreads();
    float s1 = b2[threadIdx.x], s2 = s1;
    for (int j = 0; j < R_; ++j) {
        float w = w2[threadIdx.x * R_ + j];
        s1 = fmaf(w, ha[j], s1);
        s2 = fmaf(w, hm[j], s2);
    }
    att[b * C_ + threadIdx.x] = sigmoidf_(s1) + sigmoidf_(s2);
}

// 3-step heat diffusion with reflect padding, then sigmoid. One block per image,
// two 64 KiB LDS buffers (dynamic, 128 KiB total).
__global__ void k_heat(const float* __restrict__ temp, const float* __restrict__ alphap,
                       const float* __restrict__ lapp, float* __restrict__ heat) {
    extern __shared__ float sh[];
    float* s0 = sh;
    float* s1 = sh + HW_;
    int b = blockIdx.x;
    const float* t = temp + b * HW_;
    for (int i = threadIdx.x; i < HW_; i += 256) s0[i] = t[i];
    float alpha = *alphap;
    float l0 = lapp[0], l1 = lapp[1], l2 = lapp[2],
          l3 = lapp[3], l4 = lapp[4], l5 = lapp[5],
          l6 = lapp[6], l7 = lapp[7], l8 = lapp[8];
    __syncthreads();
    float* src = s0;
    float* dst = s1;
    for (int step = 0; step < 3; ++step) {
        for (int i = threadIdx.x; i < HW_; i += 256) {
            int h = i >> 7, w = i & 127;
            int hm = h ? h - 1 : 1;
            int hp = (h < H_ - 1) ? h + 1 : H_ - 2;
            int wm = w ? w - 1 : 1;
            int wp = (w < W_ - 1) ? w + 1 : W_ - 2;
            float lap = l0 * src[(hm << 7) + wm] + l1 * src[(hm << 7) + w] + l2 * src[(hm << 7) + wp]
                      + l3 * src[(h  << 7) + wm] + l4 * src[(h  << 7) + w] + l5 * src[(h  << 7) + wp]
                      + l6 * src[(hp << 7) + wm] + l7 * src[(hp << 7) + w] + l8 * src[(hp << 7) + wp];
            dst[i] = fmaf(alpha, lap, src[i]);
        }
        __syncthreads();
        float* tm = src; src = dst; dst = tm;
    }
    float* hb = heat + b * HW_;
    for (int i = threadIdx.x; i < HW_; i += 256) hb[i] = sigmoidf_(src[i]);
}

// out[b,c,hw] = x[b,c,hw] * sigmoid(att[b,c] * heat[b,hw]). One block per (b,c).
__global__ void k_out(const float* __restrict__ x, const float* __restrict__ att,
                      const float* __restrict__ heat, float* __restrict__ out) {
    int bc = blockIdx.x;
    int b = bc >> 8;
    float a = att[bc];
    const float4* px = (const float4*)(x + (size_t)bc * HW_);
    const float4* ph = (const float4*)(heat + b * HW_);
    float4* po = (float4*)(out + (size_t)bc * HW_);
    for (int i = threadIdx.x; i < HW_ / 4; i += 256) {
        float4 v = px[i];
        float4 h = ph[i];
        float4 r;
        r.x = v.x * sigmoidf_(a * h.x);
        r.y = v.y * sigmoidf_(a * h.y);
        r.z = v.z * sigmoidf_(a * h.z);
        r.w = v.w * sigmoidf_(a * h.w);
        po[i] = r;
    }
}

extern "C" void kernel_launch(void* const* d_in, const int* in_sizes, int n_in,
                              void* d_out, int out_size, void* d_ws, size_t ws_size,
                              hipStream_t stream) {
    const float* x     = (const float*)d_in[0];
    const float* dct_w = (const float*)d_in[1];
    const float* w1    = (const float*)d_in[2];
    const float* b1    = (const float*)d_in[3];
    const float* w2    = (const float*)d_in[4];
    const float* b2    = (const float*)d_in[5];
    const float* alpha = (const float*)d_in[6];
    const float* lap   = (const float*)d_in[7];
    float* out = (float*)d_out;

    float* ws   = (float*)d_ws;
    float* m    = ws;            // 256
    float* yavg = ws + 256;      // 2048
    float* ymax = ws + 2304;     // 2048
    float* att  = ws + 4352;     // 2048
    float* temp = ws + 6400;     // 131072
    float* heat = ws + 137472;   // 131072

    k_colmean<<<1, 256, 0, stream>>>(dct_w, m);
    k_colstats<<<B_ * C_, 256, 0, stream>>>(x, yavg, ymax);
    k_temp<<<B_ * 32, 256, 0, stream>>>(x, m, temp);
    k_fc<<<B_, 256, 0, stream>>>(yavg, ymax, w1, b1, w2, b2, att);
    k_heat<<<B_, 256, 2 * HW_ * sizeof(float), stream>>>(temp, alpha, lap, heat);
    k_out<<<B_ * C_, 256, 0, stream>>>(x, att, heat, out);
}